// Round 9
// baseline (255.617 us; speedup 1.0000x reference)
//
#include <hip/hip_runtime.h>
#include <cstdint>
#include <cstddef>

// MultiHeadAttention: B=4, S=2048, D=768, H=16, Dh=48, fp32 I/O.
// bf16 MFMA: cvt_all -> fused QKV GEMM -> split-K flash-attn + combine -> out GEMM
// v14: SPLIT-K x2 attention (TLP lever). Evidence r3-r8: attn wall ~= SUM of
// pipe demands (MFMA 28% + VALU 54%) -- per-wave serial QK->exp2->pack->PV
// chains with only 4 chains/SIMD. Total wave count is fixed by q-rows unless
// we split keys. This softmax has NO running max (raw exp2 of scaled scores),
// so disjoint-key partials combine EXACTLY: O=O0+O1, lsum=lsum0+lsum1 (lsum
// rides in the dh=48 ones-row col). 2048 blocks x 64-key tiles (14KB LDS) ->
// 7 blocks/CU residency (~28 waves/CU vs 16). Combine kernel: 1024 blocks,
// (p0+p1)/(l0+l1) -> bf16 ao. Runtime fallback: if ws_size can't fit the 64MB
// f32 partial buffer, launch the v13b single-pass attn (this round's passing
// kernel) -- worst case reproduces 245us exactly.
// GEMMs: BK=64 (r8: neutral, kept). attn fallback: v11/128-tile verbatim.

typedef short s8v __attribute__((ext_vector_type(8)));    // 8 x bf16 (4 VGPRs)
typedef float f4v __attribute__((ext_vector_type(4)));    // 16x16 accumulator
typedef float f16v __attribute__((ext_vector_type(16)));  // 32x32 accumulator

static constexpr int Bn = 4, Sn = 2048, Dn = 768, Hn = 16, DhN = 48, Dp = 64;
static constexpr int MS = Bn * Sn;  // 8192 rows

#define MFMA16(a, b, c) __builtin_amdgcn_mfma_f32_16x16x32_bf16((a), (b), (c), 0, 0, 0)
#define MFMA32(a, b, c) __builtin_amdgcn_mfma_f32_32x32x16_bf16((a), (b), (c), 0, 0, 0)

__device__ __forceinline__ int swz4(int r) { return (r + (r >> 2)) & 3; }

__device__ __forceinline__ ushort f2b(float f) {
  return (ushort)((__builtin_bit_cast(uint32_t, f) + 0x8000u) >> 16);
}
// pack hi16(a+0x8000), hi16(b+0x8000) via v_perm_b32 (a -> low half)
__device__ __forceinline__ uint32_t packbf(float a, float b) {
  uint32_t ua = __builtin_bit_cast(uint32_t, a) + 0x8000u;
  uint32_t ub = __builtin_bit_cast(uint32_t, b) + 0x8000u;
  return __builtin_amdgcn_perm(ub, ua, 0x07060302u);
}
// swap upper 32 lanes of a with lower 32 lanes of b (in place, both usable)
__device__ __forceinline__ void pl32swap(uint32_t& a, uint32_t& b) {
  asm("v_permlane32_swap_b32 %0, %1" : "+v"(a), "+v"(b));
}
__device__ __forceinline__ float fexp2(float x) {
  return __builtin_amdgcn_exp2f(x);
}
__device__ __forceinline__ void gload_lds16(const ushort* g, ushort* l) {
  __builtin_amdgcn_global_load_lds(
      (const __attribute__((address_space(1))) uint32_t*)g,
      (__attribute__((address_space(3))) uint32_t*)l, 16, 0, 0);
}

// One launch converts x (6144 blocks) + 4 weights (4*576 blocks) to bf16.
__global__ void cvt_all(const float* __restrict__ x,
                        const float* __restrict__ wq, const float* __restrict__ wk,
                        const float* __restrict__ wv, const float* __restrict__ wo,
                        ushort* __restrict__ xb, ushort* __restrict__ wqkv,
                        ushort* __restrict__ wob) {
  const int bid = blockIdx.x;
  const float* src;
  ushort* dst;
  int i;
  if (bid < 6144) {
    src = x; dst = xb; i = bid * 256 + threadIdx.x;
  } else {
    const int r = (bid - 6144) / 576;
    i = ((bid - 6144) % 576) * 256 + threadIdx.x;
    src = (r == 0) ? wq : (r == 1) ? wk : (r == 2) ? wv : wo;
    dst = (r < 3) ? (wqkv + (size_t)r * Dn * Dn) : wob;
  }
  float4 f = ((const float4*)src)[i];
  ushort4 o = { f2b(f.x), f2b(f.y), f2b(f.z), f2b(f.w) };
  ((ushort4*)dst)[i] = o;
}

// ---- Fused QKV GEMM (A=W, B=x so acc regs = 4 consecutive n). Swizzled LDS.
// BK=64: 12 K-iters, 8 gload_lds/thread/iter, 2 K-substeps of 16 MFMA.
__global__ __launch_bounds__(256) void gemm_qkv(
    const ushort* __restrict__ A, const ushort* __restrict__ W,
    const float* __restrict__ bq, const float* __restrict__ bk, const float* __restrict__ bv,
    ushort* __restrict__ outq, ushort* __restrict__ outk, ushort* __restrict__ outv,
    float qscale) {
  __shared__ __align__(16) ushort As[128][64];   // x rows
  __shared__ __align__(16) ushort Bs[128][64];   // W rows
  const int tid = threadIdx.x, lane = tid & 63, wave = tid >> 6;
  const int l15 = lane & 15, g = lane >> 4;
  const int m0 = blockIdx.y * 128, n0 = blockIdx.x * 128;
  const int wqm = (wave >> 1) * 64;   // weight-dim quadrant
  const int wqx = (wave & 1) * 64;    // x-dim quadrant
  f4v acc[4][4] = {};                 // [i=wtile][j=xtile]

  const ushort* agp[4];
  const ushort* bgp[4];
  ushort* lap[4];
  ushort* lbp[4];
#pragma unroll
  for (int q = 0; q < 4; ++q) {
    const int slot = q * 256 + wave * 64 + lane;   // 0..1023
    const int r = slot >> 3, sc = slot & 7;
    const int u = ((((sc & 3) ^ swz4(r & 15)) | (sc & 4)) ^ ((r & 1) << 2)) * 8;
    agp[q] = A + (size_t)(m0 + r) * Dn + u;
    bgp[q] = W + (size_t)(n0 + r) * Dn + u;
    lap[q] = &As[0][0] + slot * 8;
    lbp[q] = &Bs[0][0] + slot * 8;
  }
  const int fcol = (g ^ swz4(l15)) * 8;
  const int par = l15 & 1;

  for (int k0 = 0; k0 < Dn; k0 += 64) {
    __syncthreads();
#pragma unroll
    for (int q = 0; q < 4; ++q) {
      gload_lds16(agp[q] + k0, lap[q]);
      gload_lds16(bgp[q] + k0, lbp[q]);
    }
    __syncthreads();
#pragma unroll
    for (int h = 0; h < 2; ++h) {
      const int fc = fcol + 32 * (h ^ par);   // holds global k-substep h
      s8v wf[4], xf[4];
#pragma unroll
      for (int i = 0; i < 4; ++i) wf[i] = *(const s8v*)&Bs[wqm + i * 16 + l15][fc];
#pragma unroll
      for (int j = 0; j < 4; ++j) xf[j] = *(const s8v*)&As[wqx + j * 16 + l15][fc];
#pragma unroll
      for (int i = 0; i < 4; ++i)
#pragma unroll
        for (int j = 0; j < 4; ++j) acc[i][j] = MFMA16(wf[i], xf[j], acc[i][j]);
    }
  }

  const int region = blockIdx.x / 6;        // uniform per block
  const int nbase = n0 - region * 768;
  const float* bias = (region == 0) ? bq : (region == 1) ? bk : bv;
#pragma unroll
  for (int i = 0; i < 4; ++i) {
    const int n = nbase + wqm + i * 16 + g * 4;   // 4 consecutive n, same head
    const float4 b4 = *(const float4*)&bias[n];
    const int h = n / DhN, dh = n - h * DhN;
#pragma unroll
    for (int j = 0; j < 4; ++j) {
      const int s = m0 + wqx + j * 16 + l15;
      const int b = s >> 11, srow = s & 2047;
      const int bh = b * Hn + h;
      float v0 = acc[i][j][0] + b4.x, v1 = acc[i][j][1] + b4.y;
      float v2 = acc[i][j][2] + b4.z, v3 = acc[i][j][3] + b4.w;
      if (region == 0) { v0 *= qscale; v1 *= qscale; v2 *= qscale; v3 *= qscale; }
      if (region < 2) {
        ushort4 o = { f2b(v0), f2b(v1), f2b(v2), f2b(v3) };
        ushort* dst = region ? outk : outq;
        *(ushort4*)&dst[((size_t)bh * Sn + srow) * Dp + dh] = o;
      } else {
        outv[((size_t)bh * DhN + dh + 0) * Sn + srow] = f2b(v0);
        outv[((size_t)bh * DhN + dh + 1) * Sn + srow] = f2b(v1);
        outv[((size_t)bh * DhN + dh + 2) * Sn + srow] = f2b(v2);
        outv[((size_t)bh * DhN + dh + 3) * Sn + srow] = f2b(v3);
      }
    }
  }
}

// ---- Out projection GEMM (swapped operands, float4 stores). BK=64.
__global__ __launch_bounds__(256) void gemm_out(
    const ushort* __restrict__ A, const ushort* __restrict__ W,
    const float* __restrict__ bias, float* __restrict__ out) {
  __shared__ __align__(16) ushort As[128][64];
  __shared__ __align__(16) ushort Bs[128][64];
  const int tid = threadIdx.x, lane = tid & 63, wave = tid >> 6;
  const int l15 = lane & 15, g = lane >> 4;
  const int m0 = blockIdx.y * 128, n0 = blockIdx.x * 128;
  const int wqm = (wave >> 1) * 64;
  const int wqx = (wave & 1) * 64;
  f4v acc[4][4] = {};

  const ushort* agp[4];
  const ushort* bgp[4];
  ushort* lap[4];
  ushort* lbp[4];
#pragma unroll
  for (int q = 0; q < 4; ++q) {
    const int slot = q * 256 + wave * 64 + lane;   // 0..1023
    const int r = slot >> 3, sc = slot & 7;
    const int u = ((((sc & 3) ^ swz4(r & 15)) | (sc & 4)) ^ ((r & 1) << 2)) * 8;
    agp[q] = A + (size_t)(m0 + r) * Dn + u;
    bgp[q] = W + (size_t)(n0 + r) * Dn + u;
    lap[q] = &As[0][0] + slot * 8;
    lbp[q] = &Bs[0][0] + slot * 8;
  }
  const int fcol = (g ^ swz4(l15)) * 8;
  const int par = l15 & 1;

  for (int k0 = 0; k0 < Dn; k0 += 64) {
    __syncthreads();
#pragma unroll
    for (int q = 0; q < 4; ++q) {
      gload_lds16(agp[q] + k0, lap[q]);
      gload_lds16(bgp[q] + k0, lbp[q]);
    }
    __syncthreads();
#pragma unroll
    for (int h = 0; h < 2; ++h) {
      const int fc = fcol + 32 * (h ^ par);
      s8v wf[4], xf[4];
#pragma unroll
      for (int i = 0; i < 4; ++i) wf[i] = *(const s8v*)&Bs[wqm + i * 16 + l15][fc];
#pragma unroll
      for (int j = 0; j < 4; ++j) xf[j] = *(const s8v*)&As[wqx + j * 16 + l15][fc];
#pragma unroll
      for (int i = 0; i < 4; ++i)
#pragma unroll
        for (int j = 0; j < 4; ++j) acc[i][j] = MFMA16(wf[i], xf[j], acc[i][j]);
    }
  }

#pragma unroll
  for (int i = 0; i < 4; ++i) {
    const int n = n0 + wqm + i * 16 + g * 4;
    const float4 b4 = *(const float4*)&bias[n];
#pragma unroll
    for (int j = 0; j < 4; ++j) {
      const int s = m0 + wqx + j * 16 + l15;
      float4 o4 = { acc[i][j][0] + b4.x, acc[i][j][1] + b4.y,
                    acc[i][j][2] + b4.z, acc[i][j][3] + b4.w };
      *(float4*)&out[(size_t)s * Dn + n] = o4;
    }
  }
}

// ---- Split-K flash attention. grid (16 qtiles, 64 bh, 2 khalf), block 256
// (4 waves x 32 q). Each block: 1024 keys of its half, 16 x 64-key tiles
// (14KB LDS -> 7 blocks/CU residency, ~28 waves/CU: the TLP lever).
// No-max exp2 softmax => partials over disjoint key ranges combine exactly.
// Epilogue: UNNORMALIZED f32 partial [128 q][64 dh] to pbuf (lsum at dh=48
// via the ones-row MFMA trick). XCD swizzle on (x,y) as before; z keeps the
// same head's two halves on the same XCD (better L2 reuse).
__global__ __launch_bounds__(256) void attn_split(
    const ushort* __restrict__ qg, const ushort* __restrict__ kg,
    const ushort* __restrict__ vg, float* __restrict__ pbuf) {
  __shared__ __align__(16) ushort Ka[64][32];
  __shared__ __align__(16) ushort Kb[64][16];
  __shared__ __align__(16) ushort Vs[64][64];
  const int tid = threadIdx.x;
  const int lane = tid & 63;
  const int wave = tid >> 6;          // 0..3
  const int l31 = lane & 31;
  const int h = lane >> 5;            // 0..1
  const int kh = blockIdx.z;          // key half
  const int lin = blockIdx.x + (blockIdx.y << 4);
  const int k8 = lin >> 3;
  const int bh = (lin & 7) * 8 + (k8 >> 4);
  const int q0 = (k8 & 15) * 128;
  const ushort* qb = qg + (size_t)bh * Sn * Dp;
  const ushort* kb = kg + (size_t)bh * Sn * Dp + (size_t)kh * 1024 * Dp;
  const ushort* vb = vg + (size_t)bh * DhN * Sn + kh * 1024;

  // static V rows 48..63: row 48 = 1.0 (lsum via MFMA), rest 0
#pragma unroll
  for (int t = 0; t < 2; ++t) {
    const int idx = tid + t * 256;            // 0..511 dwords over rows 48..63
    const int row = 48 + (idx >> 5);
    ((uint32_t*)&Vs[row][0])[idx & 31] = (row == 48) ? 0x3F803F80u : 0u;
  }

  // Q B-frags (n=q=lane&31, k=dh): kc 0..2 covers dh 0..47 (pad skipped)
  s8v qf[3];
#pragma unroll
  for (int kc = 0; kc < 3; ++kc)
    qf[kc] = *(const s8v*)(qb + (size_t)(q0 + wave * 32 + l31) * Dp + kc * 16 + h * 8);

  // DMA: 12 x 1KB chunks, wave w takes c = w + 4t (t=0..2) -> exactly 3 each.
  const ushort* gsrc[3];
  ushort* ldst[3];
  int gstep[3];
#pragma unroll
  for (int t = 0; t < 3; ++t) {
    const int c = wave + 4 * t;
    if (c < 4) {            // Ka: rows 16c..16c+15, dh 0..31 (16 rows x 4 slots)
      const int row = 16 * c + (lane >> 2), j = lane & 3;
      gsrc[t] = kb + (size_t)row * Dp + (j ^ ((row >> 1) & 3)) * 8;
      ldst[t] = &Ka[0][0] + 16 * c * 32 + lane * 8;
      gstep[t] = 64 * Dp;
    } else if (c < 6) {     // Kb: rows 32(c-4)..+31, dh 32..47 (32 rows x 2 slots)
      const int row = 32 * (c - 4) + (lane >> 1), j = lane & 1;
      gsrc[t] = kb + (size_t)row * Dp + 32 + (j ^ ((row >> 2) & 1)) * 8;
      ldst[t] = &Kb[0][0] + 32 * (c - 4) * 16 + lane * 8;
      gstep[t] = 64 * Dp;
    } else {                // V: rows 8(c-6)..+7 (8 rows x 8 slots)
      const int row = 8 * (c - 6) + (lane >> 3), j = lane & 7;
      gsrc[t] = vb + (size_t)row * Sn + (j ^ (row & 7)) * 8;
      ldst[t] = &Vs[0][0] + 8 * (c - 6) * 64 + lane * 8;
      gstep[t] = 64;
    }
  }

  f16v o0 = {}, o1 = {};   // O cols dh 0..31 / dh 32..63 (col 16 of o1 = lsum)

  for (int kt = 0; kt < 1024; kt += 64) {
    __syncthreads();
#pragma unroll
    for (int t = 0; t < 3; ++t) {
      gload_lds16(gsrc[t], ldst[t]);
      gsrc[t] += gstep[t];
    }
    __syncthreads();

#pragma unroll
    for (int mg = 0; mg < 2; ++mg) {        // key group: 32 keys
      const int row = 32 * mg + l31;        // key for A-frag
      const int s1 = (l31 >> 1) & 3, s2 = (l31 >> 2) & 1;
      s8v a0 = *(const s8v*)&Ka[row][((0 | h) ^ s1) * 8];
      s8v a1 = *(const s8v*)&Ka[row][((2 | h) ^ s1) * 8];
      s8v a2 = *(const s8v*)&Kb[row][((h) ^ s2) * 8];
      f16v sc = {};
      sc = MFMA32(a0, qf[0], sc);
      sc = MFMA32(a1, qf[1], sc);
      sc = MFMA32(a2, qf[2], sc);           // S^T: col=q(lane&31), row=key(reg,h)
      float p[16];
#pragma unroll
      for (int r = 0; r < 16; ++r) p[r] = fexp2(sc[r]);

#pragma unroll
      for (int c2 = 0; c2 < 2; ++c2) {      // 16-key chunks of this group
        const int rb = 8 * c2;
        uint32_t w0 = packbf(p[rb + 0], p[rb + 1]);
        uint32_t w1 = packbf(p[rb + 2], p[rb + 3]);
        uint32_t w2 = packbf(p[rb + 4], p[rb + 5]);
        uint32_t w3 = packbf(p[rb + 6], p[rb + 7]);
        pl32swap(w0, w2);
        pl32swap(w1, w3);
        uint4 af = { w0, w1, w2, w3 };
        const s8v pa = __builtin_bit_cast(s8v, af);
        const int kcv = 2 * mg + c2;        // 16-key chunk index in the 64-key tile
        const int vc = ((2 * kcv + h) ^ (l31 & 7)) * 8;
        const s8v v0 = *(const s8v*)&Vs[l31][vc];
        const s8v v1 = *(const s8v*)&Vs[32 + l31][vc];
        o0 = MFMA32(pa, v0, o0);
        o1 = MFMA32(pa, v1, o1);
      }
    }
  }

  // unnormalized f32 partial: pbuf[kh][bh][qt][q 0..127][dh 0..63]
  const int qt = q0 >> 7;
  float* pb = pbuf + ((size_t)kh * 1024 + bh * 16 + qt) * 8192;
#pragma unroll
  for (int r = 0; r < 16; ++r) {
    const int q = (r & 3) + 8 * (r >> 2) + 4 * h;
    const int sl = wave * 32 + q;
    pb[sl * 64 + l31] = o0[r];
    pb[sl * 64 + 32 + l31] = o1[r];
  }
}

// ---- Combine: out = (p0+p1) / (lsum0+lsum1), bf16 store to ao layout.
// grid 1024 = (bh*16+qt); block 256; 1536 float4-groups (128 q x 12) each.
__global__ __launch_bounds__(256) void attn_combine(
    const float* __restrict__ pb, ushort* __restrict__ og) {
  const int bid = blockIdx.x;           // bh*16 + qt
  const int bh = bid >> 4, qt = bid & 15;
  const int b = bh >> 4, hh = bh & 15;
  const float* p0 = pb + (size_t)bid * 8192;
  const float* p1 = p0 + (size_t)1024 * 8192;
  const int tid = threadIdx.x;
#pragma unroll
  for (int it = 0; it < 6; ++it) {
    const int i4 = tid + 256 * it;      // 0..1535
    const int q = i4 / 12, c4 = i4 - q * 12;
    const float l = p0[q * 64 + 48] + p1[q * 64 + 48];
    const float inv = 1.0f / l;
    const float4 a = *(const float4*)&p0[q * 64 + c4 * 4];
    const float4 c = *(const float4*)&p1[q * 64 + c4 * 4];
    ushort4 o = { f2b((a.x + c.x) * inv), f2b((a.y + c.y) * inv),
                  f2b((a.z + c.z) * inv), f2b((a.w + c.w) * inv) };
    *(ushort4*)&og[((size_t)(b * Sn + qt * 128 + q)) * Dn + hh * DhN + c4 * 4] = o;
  }
}

// ---- Fallback single-pass flash attention (v11/v13b, passing, verbatim).
__global__ __launch_bounds__(256) void attn_kernel(
    const ushort* __restrict__ qg, const ushort* __restrict__ kg,
    const ushort* __restrict__ vg, ushort* __restrict__ og) {
  __shared__ __align__(16) ushort Ka[128][32];
  __shared__ __align__(16) ushort Kb[128][16];
  __shared__ __align__(16) ushort Vs[64][128];
  const int tid = threadIdx.x;
  const int lane = tid & 63;
  const int wave = tid >> 6;          // 0..3
  const int l31 = lane & 31;
  const int h = lane >> 5;            // 0..1
  const int lin = blockIdx.x + (blockIdx.y << 4);
  const int k8 = lin >> 3;
  const int bh = (lin & 7) * 8 + (k8 >> 4);
  const int q0 = (k8 & 15) * 128;
  const ushort* qb = qg + (size_t)bh * Sn * Dp;
  const ushort* kb = kg + (size_t)bh * Sn * Dp;
  const ushort* vb = vg + (size_t)bh * DhN * Sn;

#pragma unroll
  for (int t = 0; t < 4; ++t) {
    const int idx = tid + t * 256;            // 0..1023 dwords
    const int row = 48 + (idx >> 6);
    ((uint32_t*)&Vs[row][0])[idx & 63] = (row == 48) ? 0x3F803F80u : 0u;
  }

  s8v qf[3];
#pragma unroll
  for (int kc = 0; kc < 3; ++kc)
    qf[kc] = *(const s8v*)(qb + (size_t)(q0 + wave * 32 + l31) * Dp + kc * 16 + h * 8);

  const ushort* gsrc[6];
  ushort* ldst[6];
  int gstep[6];
#pragma unroll
  for (int t = 0; t < 6; ++t) {
    const int c = wave + 4 * t;
    if (c < 8) {            // Ka: rows 16c..16c+15, dh 0..31
      const int row = 16 * c + (lane >> 2), j = lane & 3;
      gsrc[t] = kb + (size_t)row * Dp + (j ^ ((row >> 1) & 3)) * 8;
      ldst[t] = &Ka[0][0] + 16 * c * 32 + lane * 8;
      gstep[t] = 128 * Dp;
    } else if (c < 12) {    // Kb: rows 32(c-8)..+31, dh 32..47
      const int row = 32 * (c - 8) + (lane >> 1), j = lane & 1;
      gsrc[t] = kb + (size_t)row * Dp + 32 + (j ^ ((row >> 2) & 1)) * 8;
      ldst[t] = &Kb[0][0] + 32 * (c - 8) * 16 + lane * 8;
      gstep[t] = 128 * Dp;
    } else {                // V: dh rows 4(c-12)..+3, 128 keys (16 granules)
      const int row = 4 * (c - 12) + (lane >> 4), j = lane & 15;
      gsrc[t] = vb + (size_t)row * Sn + (j ^ (row & 7)) * 8;
      ldst[t] = &Vs[0][0] + 4 * (c - 12) * 128 + lane * 8;
      gstep[t] = 128;
    }
  }

  f16v o0 = {}, o1 = {};

  for (int kt = 0; kt < Sn; kt += 128) {
    __syncthreads();
#pragma unroll
    for (int t = 0; t < 6; ++t) {
      gload_lds16(gsrc[t], ldst[t]);
      gsrc[t] += gstep[t];
    }
    __syncthreads();

#pragma unroll
    for (int mg = 0; mg < 4; ++mg) {        // key group: 32 keys
      const int row = 32 * mg + l31;
      const int s1 = (l31 >> 1) & 3, s2 = (l31 >> 2) & 1;
      s8v a0 = *(const s8v*)&Ka[row][((0 | h) ^ s1) * 8];
      s8v a1 = *(const s8v*)&Ka[row][((2 | h) ^ s1) * 8];
      s8v a2 = *(const s8v*)&Kb[row][((h) ^ s2) * 8];
      f16v sc = {};
      sc = MFMA32(a0, qf[0], sc);
      sc = MFMA32(a1, qf[1], sc);
      sc = MFMA32(a2, qf[2], sc);
      float p[16];
#pragma unroll
      for (int r = 0; r < 16; ++r) p[r] = fexp2(sc[r]);

#pragma unroll
      for (int c2 = 0; c2 < 2; ++c2) {
        const int rb = 8 * c2;
        uint32_t w0 = packbf(p[rb + 0], p[rb + 1]);
        uint32_t w1 = packbf(p[rb + 2], p[rb + 3]);
        uint32_t w2 = packbf(p[rb + 4], p[rb + 5]);
        uint32_t w3 = packbf(p[rb + 6], p[rb + 7]);
        pl32swap(w0, w2);
        pl32swap(w1, w3);
        uint4 af = { w0, w1, w2, w3 };
        const s8v pa = __builtin_bit_cast(s8v, af);
        const int kcv = 2 * mg + c2;
        const int vc = ((2 * kcv + h) ^ (l31 & 7)) * 8;
        const s8v v0 = *(const s8v*)&Vs[l31][vc];
        const s8v v1 = *(const s8v*)&Vs[32 + l31][vc];
        o0 = MFMA32(pa, v0, o0);
        o1 = MFMA32(pa, v1, o1);
      }
    }
  }

  const int b = bh >> 4, hh = bh & 15;
#pragma unroll
  for (int r = 0; r < 16; ++r) {
    const int q = (r & 3) + 8 * (r >> 2) + 4 * h;
    const float lsum = __shfl(o1[r], 16 + (lane & 32), 64);
    const float inv = 1.0f / lsum;
    const int s = q0 + wave * 32 + q;
    const size_t base = ((size_t)(b * Sn + s)) * Dn + hh * DhN;
    og[base + l31] = f2b(o0[r] * inv);
    if (l31 < 16) og[base + 32 + l31] = f2b(o1[r] * inv);
  }
}

extern "C" void kernel_launch(void* const* d_in, const int* in_sizes, int n_in,
                              void* d_out, int out_size, void* d_ws, size_t ws_size,
                              hipStream_t stream) {
  (void)in_sizes; (void)n_in; (void)out_size;
  const float* x  = (const float*)d_in[0];
  const float* Wq = (const float*)d_in[1];
  const float* bq = (const float*)d_in[2];
  const float* Wk = (const float*)d_in[3];
  const float* bk = (const float*)d_in[4];
  const float* Wv = (const float*)d_in[5];
  const float* bv = (const float*)d_in[6];
  const float* Wo = (const float*)d_in[7];
  const float* bo = (const float*)d_in[8];

  size_t off = 0;
  auto alloc = [&](size_t bytes) {
    void* p = (char*)d_ws + off;
    off += (bytes + 255) & ~(size_t)255;
    return p;
  };
  ushort* xb    = (ushort*)alloc((size_t)MS * Dn * 2);
  ushort* Wqkvb = (ushort*)alloc((size_t)3 * Dn * Dn * 2);
  ushort* Wob   = (ushort*)alloc((size_t)Dn * Dn * 2);
  ushort* qbuf  = (ushort*)alloc((size_t)Bn * Hn * Sn * Dp * 2);
  ushort* kbuf  = (ushort*)alloc((size_t)Bn * Hn * Sn * Dp * 2);
  ushort* vbuf  = (ushort*)alloc((size_t)Bn * Hn * DhN * Sn * 2);
  ushort* ao    = (ushort*)alloc((size_t)MS * Dn * 2);
  float*  pbuf  = (float*)alloc((size_t)2 * 1024 * 128 * 64 * 4);  // 64MB partials
  const bool split = (off <= ws_size);

  cvt_all<<<6144 + 4 * 576, 256, 0, stream>>>(x, Wq, Wk, Wv, Wo, xb, Wqkvb, Wob);

  const dim3 blk(256);
  // scale = log2(e)/sqrt(48): softmax computed in exp2 domain
  const float qscale = 0.20823510929813633f;
  gemm_qkv<<<dim3(18, MS / 128), blk, 0, stream>>>(xb, Wqkvb, bq, bk, bv,
                                                   qbuf, kbuf, vbuf, qscale);

  if (split) {
    attn_split<<<dim3(Sn / 128, Bn * Hn, 2), blk, 0, stream>>>(qbuf, kbuf, vbuf, pbuf);
    attn_combine<<<dim3(Bn * Hn * 16), blk, 0, stream>>>(pbuf, ao);
  } else {
    attn_kernel<<<dim3(Sn / 128, Bn * Hn), blk, 0, stream>>>(qbuf, kbuf, vbuf, ao);
  }

  gemm_out<<<dim3(6, MS / 128), blk, 0, stream>>>(ao, Wob, bo, (float*)d_out);
}

// Round 10
// 237.800 us; speedup vs baseline: 1.0749x; 1.0749x over previous
//
#include <hip/hip_runtime.h>
#include <cstdint>
#include <cstddef>

// MultiHeadAttention: B=4, S=2048, D=768, H=16, Dh=48, fp32 I/O.
// bf16 MFMA: cvt_all -> fused QKV GEMM -> in-block split-K flash-attn -> out GEMM
// v15: r9 proved split-K helps the attn kernel (87.8 -> 78.4us, MfmaUtil 29->33)
// but the 64MB f32 partial round-trip + combine kernel (~20us) netted -10us.
// This round fuses the split INTO one block: 512 threads = 2 wave-groups x 4,
// group g owns keys [1024g, 1024g+1024) with its own 14KB K/V LDS half
// (28KB total); epilogue: group 1 passes f32 partials via LDS scratch
// (aliased over dead K/V buffers, transposed layout -> conflict-free),
// group 0 adds + normalizes (EXACTLY v14's passing combine math: O=O0+O1,
// lsum rides dh=48 ones-row). No pbuf, no combine dispatch, no extra HBM.
// 4 blocks/CU x 8 waves = 32 waves/CU (2x single-pass TLP).
// GEMMs: BK=64 (r8 neutral, kept). Carried: packbf, permlane32_swap,
// XCD head swizzle, dh-pad skip, xor-swizzled frag reads.

typedef short s8v __attribute__((ext_vector_type(8)));    // 8 x bf16 (4 VGPRs)
typedef float f4v __attribute__((ext_vector_type(4)));    // 16x16 accumulator
typedef float f16v __attribute__((ext_vector_type(16)));  // 32x32 accumulator

static constexpr int Bn = 4, Sn = 2048, Dn = 768, Hn = 16, DhN = 48, Dp = 64;
static constexpr int MS = Bn * Sn;  // 8192 rows

#define MFMA16(a, b, c) __builtin_amdgcn_mfma_f32_16x16x32_bf16((a), (b), (c), 0, 0, 0)
#define MFMA32(a, b, c) __builtin_amdgcn_mfma_f32_32x32x16_bf16((a), (b), (c), 0, 0, 0)

__device__ __forceinline__ int swz4(int r) { return (r + (r >> 2)) & 3; }

__device__ __forceinline__ ushort f2b(float f) {
  return (ushort)((__builtin_bit_cast(uint32_t, f) + 0x8000u) >> 16);
}
// pack hi16(a+0x8000), hi16(b+0x8000) via v_perm_b32 (a -> low half)
__device__ __forceinline__ uint32_t packbf(float a, float b) {
  uint32_t ua = __builtin_bit_cast(uint32_t, a) + 0x8000u;
  uint32_t ub = __builtin_bit_cast(uint32_t, b) + 0x8000u;
  return __builtin_amdgcn_perm(ub, ua, 0x07060302u);
}
// swap upper 32 lanes of a with lower 32 lanes of b (in place, both usable)
__device__ __forceinline__ void pl32swap(uint32_t& a, uint32_t& b) {
  asm("v_permlane32_swap_b32 %0, %1" : "+v"(a), "+v"(b));
}
__device__ __forceinline__ float fexp2(float x) {
  return __builtin_amdgcn_exp2f(x);
}
__device__ __forceinline__ void gload_lds16(const ushort* g, ushort* l) {
  __builtin_amdgcn_global_load_lds(
      (const __attribute__((address_space(1))) uint32_t*)g,
      (__attribute__((address_space(3))) uint32_t*)l, 16, 0, 0);
}

// One launch converts x (6144 blocks) + 4 weights (4*576 blocks) to bf16.
__global__ void cvt_all(const float* __restrict__ x,
                        const float* __restrict__ wq, const float* __restrict__ wk,
                        const float* __restrict__ wv, const float* __restrict__ wo,
                        ushort* __restrict__ xb, ushort* __restrict__ wqkv,
                        ushort* __restrict__ wob) {
  const int bid = blockIdx.x;
  const float* src;
  ushort* dst;
  int i;
  if (bid < 6144) {
    src = x; dst = xb; i = bid * 256 + threadIdx.x;
  } else {
    const int r = (bid - 6144) / 576;
    i = ((bid - 6144) % 576) * 256 + threadIdx.x;
    src = (r == 0) ? wq : (r == 1) ? wk : (r == 2) ? wv : wo;
    dst = (r < 3) ? (wqkv + (size_t)r * Dn * Dn) : wob;
  }
  float4 f = ((const float4*)src)[i];
  ushort4 o = { f2b(f.x), f2b(f.y), f2b(f.z), f2b(f.w) };
  ((ushort4*)dst)[i] = o;
}

// ---- Fused QKV GEMM (A=W, B=x so acc regs = 4 consecutive n). Swizzled LDS.
// BK=64: 12 K-iters, 8 gload_lds/thread/iter, 2 K-substeps of 16 MFMA.
__global__ __launch_bounds__(256) void gemm_qkv(
    const ushort* __restrict__ A, const ushort* __restrict__ W,
    const float* __restrict__ bq, const float* __restrict__ bk, const float* __restrict__ bv,
    ushort* __restrict__ outq, ushort* __restrict__ outk, ushort* __restrict__ outv,
    float qscale) {
  __shared__ __align__(16) ushort As[128][64];   // x rows
  __shared__ __align__(16) ushort Bs[128][64];   // W rows
  const int tid = threadIdx.x, lane = tid & 63, wave = tid >> 6;
  const int l15 = lane & 15, g = lane >> 4;
  const int m0 = blockIdx.y * 128, n0 = blockIdx.x * 128;
  const int wqm = (wave >> 1) * 64;   // weight-dim quadrant
  const int wqx = (wave & 1) * 64;    // x-dim quadrant
  f4v acc[4][4] = {};                 // [i=wtile][j=xtile]

  const ushort* agp[4];
  const ushort* bgp[4];
  ushort* lap[4];
  ushort* lbp[4];
#pragma unroll
  for (int q = 0; q < 4; ++q) {
    const int slot = q * 256 + wave * 64 + lane;   // 0..1023
    const int r = slot >> 3, sc = slot & 7;
    const int u = ((((sc & 3) ^ swz4(r & 15)) | (sc & 4)) ^ ((r & 1) << 2)) * 8;
    agp[q] = A + (size_t)(m0 + r) * Dn + u;
    bgp[q] = W + (size_t)(n0 + r) * Dn + u;
    lap[q] = &As[0][0] + slot * 8;
    lbp[q] = &Bs[0][0] + slot * 8;
  }
  const int fcol = (g ^ swz4(l15)) * 8;
  const int par = l15 & 1;

  for (int k0 = 0; k0 < Dn; k0 += 64) {
    __syncthreads();
#pragma unroll
    for (int q = 0; q < 4; ++q) {
      gload_lds16(agp[q] + k0, lap[q]);
      gload_lds16(bgp[q] + k0, lbp[q]);
    }
    __syncthreads();
#pragma unroll
    for (int h = 0; h < 2; ++h) {
      const int fc = fcol + 32 * (h ^ par);   // holds global k-substep h
      s8v wf[4], xf[4];
#pragma unroll
      for (int i = 0; i < 4; ++i) wf[i] = *(const s8v*)&Bs[wqm + i * 16 + l15][fc];
#pragma unroll
      for (int j = 0; j < 4; ++j) xf[j] = *(const s8v*)&As[wqx + j * 16 + l15][fc];
#pragma unroll
      for (int i = 0; i < 4; ++i)
#pragma unroll
        for (int j = 0; j < 4; ++j) acc[i][j] = MFMA16(wf[i], xf[j], acc[i][j]);
    }
  }

  const int region = blockIdx.x / 6;        // uniform per block
  const int nbase = n0 - region * 768;
  const float* bias = (region == 0) ? bq : (region == 1) ? bk : bv;
#pragma unroll
  for (int i = 0; i < 4; ++i) {
    const int n = nbase + wqm + i * 16 + g * 4;   // 4 consecutive n, same head
    const float4 b4 = *(const float4*)&bias[n];
    const int h = n / DhN, dh = n - h * DhN;
#pragma unroll
    for (int j = 0; j < 4; ++j) {
      const int s = m0 + wqx + j * 16 + l15;
      const int b = s >> 11, srow = s & 2047;
      const int bh = b * Hn + h;
      float v0 = acc[i][j][0] + b4.x, v1 = acc[i][j][1] + b4.y;
      float v2 = acc[i][j][2] + b4.z, v3 = acc[i][j][3] + b4.w;
      if (region == 0) { v0 *= qscale; v1 *= qscale; v2 *= qscale; v3 *= qscale; }
      if (region < 2) {
        ushort4 o = { f2b(v0), f2b(v1), f2b(v2), f2b(v3) };
        ushort* dst = region ? outk : outq;
        *(ushort4*)&dst[((size_t)bh * Sn + srow) * Dp + dh] = o;
      } else {
        outv[((size_t)bh * DhN + dh + 0) * Sn + srow] = f2b(v0);
        outv[((size_t)bh * DhN + dh + 1) * Sn + srow] = f2b(v1);
        outv[((size_t)bh * DhN + dh + 2) * Sn + srow] = f2b(v2);
        outv[((size_t)bh * DhN + dh + 3) * Sn + srow] = f2b(v3);
      }
    }
  }
}

// ---- Out projection GEMM (swapped operands, float4 stores). BK=64.
__global__ __launch_bounds__(256) void gemm_out(
    const ushort* __restrict__ A, const ushort* __restrict__ W,
    const float* __restrict__ bias, float* __restrict__ out) {
  __shared__ __align__(16) ushort As[128][64];
  __shared__ __align__(16) ushort Bs[128][64];
  const int tid = threadIdx.x, lane = tid & 63, wave = tid >> 6;
  const int l15 = lane & 15, g = lane >> 4;
  const int m0 = blockIdx.y * 128, n0 = blockIdx.x * 128;
  const int wqm = (wave >> 1) * 64;
  const int wqx = (wave & 1) * 64;
  f4v acc[4][4] = {};

  const ushort* agp[4];
  const ushort* bgp[4];
  ushort* lap[4];
  ushort* lbp[4];
#pragma unroll
  for (int q = 0; q < 4; ++q) {
    const int slot = q * 256 + wave * 64 + lane;   // 0..1023
    const int r = slot >> 3, sc = slot & 7;
    const int u = ((((sc & 3) ^ swz4(r & 15)) | (sc & 4)) ^ ((r & 1) << 2)) * 8;
    agp[q] = A + (size_t)(m0 + r) * Dn + u;
    bgp[q] = W + (size_t)(n0 + r) * Dn + u;
    lap[q] = &As[0][0] + slot * 8;
    lbp[q] = &Bs[0][0] + slot * 8;
  }
  const int fcol = (g ^ swz4(l15)) * 8;
  const int par = l15 & 1;

  for (int k0 = 0; k0 < Dn; k0 += 64) {
    __syncthreads();
#pragma unroll
    for (int q = 0; q < 4; ++q) {
      gload_lds16(agp[q] + k0, lap[q]);
      gload_lds16(bgp[q] + k0, lbp[q]);
    }
    __syncthreads();
#pragma unroll
    for (int h = 0; h < 2; ++h) {
      const int fc = fcol + 32 * (h ^ par);
      s8v wf[4], xf[4];
#pragma unroll
      for (int i = 0; i < 4; ++i) wf[i] = *(const s8v*)&Bs[wqm + i * 16 + l15][fc];
#pragma unroll
      for (int j = 0; j < 4; ++j) xf[j] = *(const s8v*)&As[wqx + j * 16 + l15][fc];
#pragma unroll
      for (int i = 0; i < 4; ++i)
#pragma unroll
        for (int j = 0; j < 4; ++j) acc[i][j] = MFMA16(wf[i], xf[j], acc[i][j]);
    }
  }

#pragma unroll
  for (int i = 0; i < 4; ++i) {
    const int n = n0 + wqm + i * 16 + g * 4;
    const float4 b4 = *(const float4*)&bias[n];
#pragma unroll
    for (int j = 0; j < 4; ++j) {
      const int s = m0 + wqx + j * 16 + l15;
      float4 o4 = { acc[i][j][0] + b4.x, acc[i][j][1] + b4.y,
                    acc[i][j][2] + b4.z, acc[i][j][3] + b4.w };
      *(float4*)&out[(size_t)s * Dn + n] = o4;
    }
  }
}

// ---- In-block split-K flash attention. grid (16, 64), block 512
// (8 waves = 2 key-groups x 4 q-waves of 32 q each). Group g: keys
// [1024g, 1024g+1024), 16 x 64-key tiles in its own LDS half (14KB:
// Ka[64][32] + Kb[64][16] + Vs[64][64]). Per-half compute = r9's passing
// attn_split body verbatim. Epilogue: group 1 -> LDS scratch (f32,
// transposed layout r*256+w4*64+lane: conflict-free, aliased over dead
// K/V buffers), group 0 adds + normalizes (lsum = dh48 ones-row col).
__global__ __launch_bounds__(512) void attn_fused(
    const ushort* __restrict__ qg, const ushort* __restrict__ kgl,
    const ushort* __restrict__ vg, ushort* __restrict__ og) {
  __shared__ __align__(16) ushort smem[2][7168];  // per half: Ka 2048 | Kb 1024 | Vs 4096
  const int tid = threadIdx.x;
  const int lane = tid & 63;
  const int wave = tid >> 6;          // 0..7
  const int w4 = wave & 3;            // q-wave within group
  const int kg = wave >> 2;           // key-half group
  const int l31 = lane & 31;
  const int h = lane >> 5;            // 0..1
  // XCD swizzle: lin%8 = XCD c; XCD c gets heads [8c,8c+8) x all q-tiles.
  const int lin = blockIdx.x + (blockIdx.y << 4);
  const int k8 = lin >> 3;
  const int bh = (lin & 7) * 8 + (k8 >> 4);
  const int q0 = (k8 & 15) * 128;
  const ushort* qb = qg + (size_t)bh * Sn * Dp;
  const ushort* kb = kgl + (size_t)bh * Sn * Dp + (size_t)kg * 1024 * Dp;
  const ushort* vb = vg + (size_t)bh * DhN * Sn + kg * 1024;
  ushort* KaH = &smem[kg][0];         // [64][32]
  ushort* KbH = &smem[kg][2048];      // [64][16]
  ushort* VsH = &smem[kg][3072];      // [64][64]

  // static V rows 48..63 (both halves): row 48 = 1.0 (lsum), rest 0.
  // Static region = ushort offset 3072 + 48*64 = 6144; 512 dwords; 512 threads.
  ((uint32_t*)&smem[0][6144])[tid] = (tid < 32) ? 0x3F803F80u : 0u;
  ((uint32_t*)&smem[1][6144])[tid] = (tid < 32) ? 0x3F803F80u : 0u;

  // Q B-frags (n=q=lane&31, k=dh): kc 0..2 covers dh 0..47 (pad skipped)
  s8v qf[3];
#pragma unroll
  for (int kc = 0; kc < 3; ++kc)
    qf[kc] = *(const s8v*)(qb + (size_t)(q0 + w4 * 32 + l31) * Dp + kc * 16 + h * 8);

  // DMA per half: 12 x 1KB chunks, q-wave w4 takes c = w4 + 4t -> 3 each.
  const ushort* gsrc[3];
  ushort* ldst[3];
  int gstep[3];
#pragma unroll
  for (int t = 0; t < 3; ++t) {
    const int c = w4 + 4 * t;
    if (c < 4) {            // Ka: rows 16c..16c+15, dh 0..31
      const int row = 16 * c + (lane >> 2), j = lane & 3;
      gsrc[t] = kb + (size_t)row * Dp + (j ^ ((row >> 1) & 3)) * 8;
      ldst[t] = KaH + 16 * c * 32 + lane * 8;
      gstep[t] = 64 * Dp;
    } else if (c < 6) {     // Kb: rows 32(c-4)..+31, dh 32..47
      const int row = 32 * (c - 4) + (lane >> 1), j = lane & 1;
      gsrc[t] = kb + (size_t)row * Dp + 32 + (j ^ ((row >> 2) & 1)) * 8;
      ldst[t] = KbH + 32 * (c - 4) * 16 + lane * 8;
      gstep[t] = 64 * Dp;
    } else {                // V: rows 8(c-6)..+7
      const int row = 8 * (c - 6) + (lane >> 3), j = lane & 7;
      gsrc[t] = vb + (size_t)row * Sn + (j ^ (row & 7)) * 8;
      ldst[t] = VsH + 8 * (c - 6) * 64 + lane * 8;
      gstep[t] = 64;
    }
  }

  f16v o0 = {}, o1 = {};   // O cols dh 0..31 / dh 32..63 (col 16 of o1 = lsum)

  for (int kt = 0; kt < 1024; kt += 64) {
    __syncthreads();
#pragma unroll
    for (int t = 0; t < 3; ++t) {
      gload_lds16(gsrc[t], ldst[t]);
      gsrc[t] += gstep[t];
    }
    __syncthreads();

#pragma unroll
    for (int mg = 0; mg < 2; ++mg) {        // key group: 32 keys
      const int row = 32 * mg + l31;        // key for A-frag
      const int s1 = (l31 >> 1) & 3, s2 = (l31 >> 2) & 1;
      s8v a0 = *(const s8v*)(KaH + row * 32 + ((0 | h) ^ s1) * 8);
      s8v a1 = *(const s8v*)(KaH + row * 32 + ((2 | h) ^ s1) * 8);
      s8v a2 = *(const s8v*)(KbH + row * 16 + ((h) ^ s2) * 8);
      f16v sc = {};
      sc = MFMA32(a0, qf[0], sc);
      sc = MFMA32(a1, qf[1], sc);
      sc = MFMA32(a2, qf[2], sc);           // S^T: col=q(lane&31), row=key(reg,h)
      float p[16];
#pragma unroll
      for (int r = 0; r < 16; ++r) p[r] = fexp2(sc[r]);

#pragma unroll
      for (int c2 = 0; c2 < 2; ++c2) {      // 16-key chunks of this group
        const int rb = 8 * c2;
        uint32_t w0 = packbf(p[rb + 0], p[rb + 1]);
        uint32_t w1 = packbf(p[rb + 2], p[rb + 3]);
        uint32_t w2 = packbf(p[rb + 4], p[rb + 5]);
        uint32_t w3 = packbf(p[rb + 6], p[rb + 7]);
        pl32swap(w0, w2);
        pl32swap(w1, w3);
        uint4 af = { w0, w1, w2, w3 };
        const s8v pa = __builtin_bit_cast(s8v, af);
        const int kcv = 2 * mg + c2;        // 16-key chunk index in 64-key tile
        const int vc = ((2 * kcv + h) ^ (l31 & 7)) * 8;
        const s8v v0 = *(const s8v*)(VsH + l31 * 64 + vc);
        const s8v v1 = *(const s8v*)(VsH + (32 + l31) * 64 + vc);
        o0 = MFMA32(pa, v0, o0);
        o1 = MFMA32(pa, v1, o1);
      }
    }
  }

  // ---- in-LDS combine (exact: disjoint-key partials add; v14-passing math).
  // scratch: 16KB f32 over dead K/V buffers, layout r*256 + w4*64 + lane
  // (lane stride 1 -> conflict-free).
  __syncthreads();
  float* scr = (float*)&smem[0][0];
  if (kg == 1) {
#pragma unroll
    for (int r = 0; r < 16; ++r) scr[r * 256 + w4 * 64 + lane] = o0[r];
  }
  __syncthreads();
  if (kg == 0) {
#pragma unroll
    for (int r = 0; r < 16; ++r) o0[r] += scr[r * 256 + w4 * 64 + lane];
  }
  __syncthreads();
  if (kg == 1) {
#pragma unroll
    for (int r = 0; r < 16; ++r) scr[r * 256 + w4 * 64 + lane] = o1[r];
  }
  __syncthreads();
  if (kg == 0) {
#pragma unroll
    for (int r = 0; r < 16; ++r) o1[r] += scr[r * 256 + w4 * 64 + lane];

    const int b = bh >> 4, hh = bh & 15;
#pragma unroll
    for (int r = 0; r < 16; ++r) {
      const int q = (r & 3) + 8 * (r >> 2) + 4 * h;
      const float lsum = __shfl(o1[r], 16 + (lane & 32), 64);  // dh48 ones row
      const float inv = 1.0f / lsum;
      const int s = q0 + w4 * 32 + q;
      const size_t base = ((size_t)(b * Sn + s)) * Dn + hh * DhN;
      og[base + l31] = f2b(o0[r] * inv);
      if (l31 < 16) og[base + 32 + l31] = f2b(o1[r] * inv);
    }
  }
}

extern "C" void kernel_launch(void* const* d_in, const int* in_sizes, int n_in,
                              void* d_out, int out_size, void* d_ws, size_t ws_size,
                              hipStream_t stream) {
  (void)in_sizes; (void)n_in; (void)out_size; (void)ws_size;
  const float* x  = (const float*)d_in[0];
  const float* Wq = (const float*)d_in[1];
  const float* bq = (const float*)d_in[2];
  const float* Wk = (const float*)d_in[3];
  const float* bk = (const float*)d_in[4];
  const float* Wv = (const float*)d_in[5];
  const float* bv = (const float*)d_in[6];
  const float* Wo = (const float*)d_in[7];
  const float* bo = (const float*)d_in[8];

  size_t off = 0;
  auto alloc = [&](size_t bytes) {
    void* p = (char*)d_ws + off;
    off += (bytes + 255) & ~(size_t)255;
    return p;
  };
  ushort* xb    = (ushort*)alloc((size_t)MS * Dn * 2);
  ushort* Wqkvb = (ushort*)alloc((size_t)3 * Dn * Dn * 2);
  ushort* Wob   = (ushort*)alloc((size_t)Dn * Dn * 2);
  ushort* qbuf  = (ushort*)alloc((size_t)Bn * Hn * Sn * Dp * 2);
  ushort* kbuf  = (ushort*)alloc((size_t)Bn * Hn * Sn * Dp * 2);
  ushort* vbuf  = (ushort*)alloc((size_t)Bn * Hn * DhN * Sn * 2);
  ushort* ao    = (ushort*)alloc((size_t)MS * Dn * 2);

  cvt_all<<<6144 + 4 * 576, 256, 0, stream>>>(x, Wq, Wk, Wv, Wo, xb, Wqkvb, Wob);

  const dim3 blk(256);
  // scale = log2(e)/sqrt(48): softmax computed in exp2 domain
  const float qscale = 0.20823510929813633f;
  gemm_qkv<<<dim3(18, MS / 128), blk, 0, stream>>>(xb, Wqkvb, bq, bk, bv,
                                                   qbuf, kbuf, vbuf, qscale);

  attn_fused<<<dim3(Sn / 128, Bn * Hn), dim3(512), 0, stream>>>(qbuf, kbuf, vbuf, ao);

  gemm_out<<<dim3(6, MS / 128), blk, 0, stream>>>(ao, Wob, bo, (float*)d_out);
}

// Round 11
// 233.166 us; speedup vs baseline: 1.0963x; 1.0199x over previous
//
#include <hip/hip_runtime.h>
#include <cstdint>
#include <cstddef>

// MultiHeadAttention: B=4, S=2048, D=768, H=16, Dh=48, fp32 I/O.
// bf16 MFMA: cvt_all -> fused QKV GEMM -> in-block split-K flash-attn -> out GEMM
// v16: + XCD-aware bijective block swizzle on BOTH GEMMs (T1; the same
// transform cut attn FETCH 5.5x in r3). nwg_qkv=1152, nwg_out=384 (both %8==0
// -> bijective chunked map valid): XCD c gets 8 consecutive m-panels x all
// n-blocks -> per-XCD working set 5.1MB/2.7MB ~ L2-sized vs ~18MB scattered.
// Pure block-id relabel: bit-identical numerics.
// attn_fused (v15, passing, 79.5us): in-block split-K, 512 thr = 2 key-groups
// x 4 q-waves; in-LDS combine; 32 waves/CU (HW cap). GEMMs BK=64.
// Carried: packbf, permlane32_swap, dh-pad skip, xor-swizzled frag reads.

typedef short s8v __attribute__((ext_vector_type(8)));    // 8 x bf16 (4 VGPRs)
typedef float f4v __attribute__((ext_vector_type(4)));    // 16x16 accumulator
typedef float f16v __attribute__((ext_vector_type(16)));  // 32x32 accumulator

static constexpr int Bn = 4, Sn = 2048, Dn = 768, Hn = 16, DhN = 48, Dp = 64;
static constexpr int MS = Bn * Sn;  // 8192 rows

#define MFMA16(a, b, c) __builtin_amdgcn_mfma_f32_16x16x32_bf16((a), (b), (c), 0, 0, 0)
#define MFMA32(a, b, c) __builtin_amdgcn_mfma_f32_32x32x16_bf16((a), (b), (c), 0, 0, 0)

__device__ __forceinline__ int swz4(int r) { return (r + (r >> 2)) & 3; }

__device__ __forceinline__ ushort f2b(float f) {
  return (ushort)((__builtin_bit_cast(uint32_t, f) + 0x8000u) >> 16);
}
// pack hi16(a+0x8000), hi16(b+0x8000) via v_perm_b32 (a -> low half)
__device__ __forceinline__ uint32_t packbf(float a, float b) {
  uint32_t ua = __builtin_bit_cast(uint32_t, a) + 0x8000u;
  uint32_t ub = __builtin_bit_cast(uint32_t, b) + 0x8000u;
  return __builtin_amdgcn_perm(ub, ua, 0x07060302u);
}
// swap upper 32 lanes of a with lower 32 lanes of b (in place, both usable)
__device__ __forceinline__ void pl32swap(uint32_t& a, uint32_t& b) {
  asm("v_permlane32_swap_b32 %0, %1" : "+v"(a), "+v"(b));
}
__device__ __forceinline__ float fexp2(float x) {
  return __builtin_amdgcn_exp2f(x);
}
__device__ __forceinline__ void gload_lds16(const ushort* g, ushort* l) {
  __builtin_amdgcn_global_load_lds(
      (const __attribute__((address_space(1))) uint32_t*)g,
      (__attribute__((address_space(3))) uint32_t*)l, 16, 0, 0);
}

// One launch converts x (6144 blocks) + 4 weights (4*576 blocks) to bf16.
__global__ void cvt_all(const float* __restrict__ x,
                        const float* __restrict__ wq, const float* __restrict__ wk,
                        const float* __restrict__ wv, const float* __restrict__ wo,
                        ushort* __restrict__ xb, ushort* __restrict__ wqkv,
                        ushort* __restrict__ wob) {
  const int bid = blockIdx.x;
  const float* src;
  ushort* dst;
  int i;
  if (bid < 6144) {
    src = x; dst = xb; i = bid * 256 + threadIdx.x;
  } else {
    const int r = (bid - 6144) / 576;
    i = ((bid - 6144) % 576) * 256 + threadIdx.x;
    src = (r == 0) ? wq : (r == 1) ? wk : (r == 2) ? wv : wo;
    dst = (r < 3) ? (wqkv + (size_t)r * Dn * Dn) : wob;
  }
  float4 f = ((const float4*)src)[i];
  ushort4 o = { f2b(f.x), f2b(f.y), f2b(f.z), f2b(f.w) };
  ((ushort4*)dst)[i] = o;
}

// ---- Fused QKV GEMM (A=W, B=x so acc regs = 4 consecutive n). Swizzled LDS.
// BK=64: 12 K-iters. XCD swizzle: nwg=1152, XCD c gets 144 consecutive cells
// = 8 m-panels x 18 n-blocks (x 1.6MB + W 3.5MB ~ one 4MB L2).
__global__ __launch_bounds__(256) void gemm_qkv(
    const ushort* __restrict__ A, const ushort* __restrict__ W,
    const float* __restrict__ bq, const float* __restrict__ bk, const float* __restrict__ bv,
    ushort* __restrict__ outq, ushort* __restrict__ outk, ushort* __restrict__ outv,
    float qscale) {
  __shared__ __align__(16) ushort As[128][64];   // x rows
  __shared__ __align__(16) ushort Bs[128][64];   // W rows
  const int tid = threadIdx.x, lane = tid & 63, wave = tid >> 6;
  const int l15 = lane & 15, g = lane >> 4;
  // XCD-aware bijective relabel: hw round-robins linear id % 8 across XCDs.
  const int lin0 = blockIdx.x + blockIdx.y * 18;        // 0..1151
  const int lin = (lin0 & 7) * 144 + (lin0 >> 3);       // XCD-chunked, bijective
  const int nx = lin % 18, my = lin / 18;
  const int m0 = my * 128, n0 = nx * 128;
  const int wqm = (wave >> 1) * 64;   // weight-dim quadrant
  const int wqx = (wave & 1) * 64;    // x-dim quadrant
  f4v acc[4][4] = {};                 // [i=wtile][j=xtile]

  const ushort* agp[4];
  const ushort* bgp[4];
  ushort* lap[4];
  ushort* lbp[4];
#pragma unroll
  for (int q = 0; q < 4; ++q) {
    const int slot = q * 256 + wave * 64 + lane;   // 0..1023
    const int r = slot >> 3, sc = slot & 7;
    const int u = ((((sc & 3) ^ swz4(r & 15)) | (sc & 4)) ^ ((r & 1) << 2)) * 8;
    agp[q] = A + (size_t)(m0 + r) * Dn + u;
    bgp[q] = W + (size_t)(n0 + r) * Dn + u;
    lap[q] = &As[0][0] + slot * 8;
    lbp[q] = &Bs[0][0] + slot * 8;
  }
  const int fcol = (g ^ swz4(l15)) * 8;
  const int par = l15 & 1;

  for (int k0 = 0; k0 < Dn; k0 += 64) {
    __syncthreads();
#pragma unroll
    for (int q = 0; q < 4; ++q) {
      gload_lds16(agp[q] + k0, lap[q]);
      gload_lds16(bgp[q] + k0, lbp[q]);
    }
    __syncthreads();
#pragma unroll
    for (int h = 0; h < 2; ++h) {
      const int fc = fcol + 32 * (h ^ par);   // holds global k-substep h
      s8v wf[4], xf[4];
#pragma unroll
      for (int i = 0; i < 4; ++i) wf[i] = *(const s8v*)&Bs[wqm + i * 16 + l15][fc];
#pragma unroll
      for (int j = 0; j < 4; ++j) xf[j] = *(const s8v*)&As[wqx + j * 16 + l15][fc];
#pragma unroll
      for (int i = 0; i < 4; ++i)
#pragma unroll
        for (int j = 0; j < 4; ++j) acc[i][j] = MFMA16(wf[i], xf[j], acc[i][j]);
    }
  }

  const int region = nx / 6;                // uniform per block
  const int nbase = n0 - region * 768;
  const float* bias = (region == 0) ? bq : (region == 1) ? bk : bv;
#pragma unroll
  for (int i = 0; i < 4; ++i) {
    const int n = nbase + wqm + i * 16 + g * 4;   // 4 consecutive n, same head
    const float4 b4 = *(const float4*)&bias[n];
    const int h = n / DhN, dh = n - h * DhN;
#pragma unroll
    for (int j = 0; j < 4; ++j) {
      const int s = m0 + wqx + j * 16 + l15;
      const int b = s >> 11, srow = s & 2047;
      const int bh = b * Hn + h;
      float v0 = acc[i][j][0] + b4.x, v1 = acc[i][j][1] + b4.y;
      float v2 = acc[i][j][2] + b4.z, v3 = acc[i][j][3] + b4.w;
      if (region == 0) { v0 *= qscale; v1 *= qscale; v2 *= qscale; v3 *= qscale; }
      if (region < 2) {
        ushort4 o = { f2b(v0), f2b(v1), f2b(v2), f2b(v3) };
        ushort* dst = region ? outk : outq;
        *(ushort4*)&dst[((size_t)bh * Sn + srow) * Dp + dh] = o;
      } else {
        outv[((size_t)bh * DhN + dh + 0) * Sn + srow] = f2b(v0);
        outv[((size_t)bh * DhN + dh + 1) * Sn + srow] = f2b(v1);
        outv[((size_t)bh * DhN + dh + 2) * Sn + srow] = f2b(v2);
        outv[((size_t)bh * DhN + dh + 3) * Sn + srow] = f2b(v3);
      }
    }
  }
}

// ---- Out projection GEMM (swapped operands, float4 stores). BK=64.
// XCD swizzle: nwg=384, XCD c gets 48 cells = 8 m-panels x 6 n-blocks
// (ao 1.6MB + Wo 1.1MB fully L2-resident).
__global__ __launch_bounds__(256) void gemm_out(
    const ushort* __restrict__ A, const ushort* __restrict__ W,
    const float* __restrict__ bias, float* __restrict__ out) {
  __shared__ __align__(16) ushort As[128][64];
  __shared__ __align__(16) ushort Bs[128][64];
  const int tid = threadIdx.x, lane = tid & 63, wave = tid >> 6;
  const int l15 = lane & 15, g = lane >> 4;
  const int lin0 = blockIdx.x + blockIdx.y * 6;         // 0..383
  const int lin = (lin0 & 7) * 48 + (lin0 >> 3);        // XCD-chunked, bijective
  const int nx = lin % 6, my = lin / 6;
  const int m0 = my * 128, n0 = nx * 128;
  const int wqm = (wave >> 1) * 64;
  const int wqx = (wave & 1) * 64;
  f4v acc[4][4] = {};

  const ushort* agp[4];
  const ushort* bgp[4];
  ushort* lap[4];
  ushort* lbp[4];
#pragma unroll
  for (int q = 0; q < 4; ++q) {
    const int slot = q * 256 + wave * 64 + lane;   // 0..1023
    const int r = slot >> 3, sc = slot & 7;
    const int u = ((((sc & 3) ^ swz4(r & 15)) | (sc & 4)) ^ ((r & 1) << 2)) * 8;
    agp[q] = A + (size_t)(m0 + r) * Dn + u;
    bgp[q] = W + (size_t)(n0 + r) * Dn + u;
    lap[q] = &As[0][0] + slot * 8;
    lbp[q] = &Bs[0][0] + slot * 8;
  }
  const int fcol = (g ^ swz4(l15)) * 8;
  const int par = l15 & 1;

  for (int k0 = 0; k0 < Dn; k0 += 64) {
    __syncthreads();
#pragma unroll
    for (int q = 0; q < 4; ++q) {
      gload_lds16(agp[q] + k0, lap[q]);
      gload_lds16(bgp[q] + k0, lbp[q]);
    }
    __syncthreads();
#pragma unroll
    for (int h = 0; h < 2; ++h) {
      const int fc = fcol + 32 * (h ^ par);
      s8v wf[4], xf[4];
#pragma unroll
      for (int i = 0; i < 4; ++i) wf[i] = *(const s8v*)&Bs[wqm + i * 16 + l15][fc];
#pragma unroll
      for (int j = 0; j < 4; ++j) xf[j] = *(const s8v*)&As[wqx + j * 16 + l15][fc];
#pragma unroll
      for (int i = 0; i < 4; ++i)
#pragma unroll
        for (int j = 0; j < 4; ++j) acc[i][j] = MFMA16(wf[i], xf[j], acc[i][j]);
    }
  }

#pragma unroll
  for (int i = 0; i < 4; ++i) {
    const int n = n0 + wqm + i * 16 + g * 4;
    const float4 b4 = *(const float4*)&bias[n];
#pragma unroll
    for (int j = 0; j < 4; ++j) {
      const int s = m0 + wqx + j * 16 + l15;
      float4 o4 = { acc[i][j][0] + b4.x, acc[i][j][1] + b4.y,
                    acc[i][j][2] + b4.z, acc[i][j][3] + b4.w };
      *(float4*)&out[(size_t)s * Dn + n] = o4;
    }
  }
}

// ---- In-block split-K flash attention (v15, passing, verbatim). grid (16, 64),
// block 512 (8 waves = 2 key-groups x 4 q-waves of 32 q each). Group g: keys
// [1024g, 1024g+1024), 16 x 64-key tiles in its own LDS half (14KB).
// Epilogue: group 1 -> LDS scratch (transposed, conflict-free), group 0 adds
// + normalizes (lsum = dh48 ones-row col). 32 waves/CU (HW cap).
__global__ __launch_bounds__(512) void attn_fused(
    const ushort* __restrict__ qg, const ushort* __restrict__ kgl,
    const ushort* __restrict__ vg, ushort* __restrict__ og) {
  __shared__ __align__(16) ushort smem[2][7168];  // per half: Ka 2048 | Kb 1024 | Vs 4096
  const int tid = threadIdx.x;
  const int lane = tid & 63;
  const int wave = tid >> 6;          // 0..7
  const int w4 = wave & 3;            // q-wave within group
  const int kg = wave >> 2;           // key-half group
  const int l31 = lane & 31;
  const int h = lane >> 5;            // 0..1
  // XCD swizzle: lin%8 = XCD c; XCD c gets heads [8c,8c+8) x all q-tiles.
  const int lin = blockIdx.x + (blockIdx.y << 4);
  const int k8 = lin >> 3;
  const int bh = (lin & 7) * 8 + (k8 >> 4);
  const int q0 = (k8 & 15) * 128;
  const ushort* qb = qg + (size_t)bh * Sn * Dp;
  const ushort* kb = kgl + (size_t)bh * Sn * Dp + (size_t)kg * 1024 * Dp;
  const ushort* vb = vg + (size_t)bh * DhN * Sn + kg * 1024;
  ushort* KaH = &smem[kg][0];         // [64][32]
  ushort* KbH = &smem[kg][2048];      // [64][16]
  ushort* VsH = &smem[kg][3072];      // [64][64]

  // static V rows 48..63 (both halves): row 48 = 1.0 (lsum), rest 0.
  ((uint32_t*)&smem[0][6144])[tid] = (tid < 32) ? 0x3F803F80u : 0u;
  ((uint32_t*)&smem[1][6144])[tid] = (tid < 32) ? 0x3F803F80u : 0u;

  // Q B-frags (n=q=lane&31, k=dh): kc 0..2 covers dh 0..47 (pad skipped)
  s8v qf[3];
#pragma unroll
  for (int kc = 0; kc < 3; ++kc)
    qf[kc] = *(const s8v*)(qb + (size_t)(q0 + w4 * 32 + l31) * Dp + kc * 16 + h * 8);

  // DMA per half: 12 x 1KB chunks, q-wave w4 takes c = w4 + 4t -> 3 each.
  const ushort* gsrc[3];
  ushort* ldst[3];
  int gstep[3];
#pragma unroll
  for (int t = 0; t < 3; ++t) {
    const int c = w4 + 4 * t;
    if (c < 4) {            // Ka: rows 16c..16c+15, dh 0..31
      const int row = 16 * c + (lane >> 2), j = lane & 3;
      gsrc[t] = kb + (size_t)row * Dp + (j ^ ((row >> 1) & 3)) * 8;
      ldst[t] = KaH + 16 * c * 32 + lane * 8;
      gstep[t] = 64 * Dp;
    } else if (c < 6) {     // Kb: rows 32(c-4)..+31, dh 32..47
      const int row = 32 * (c - 4) + (lane >> 1), j = lane & 1;
      gsrc[t] = kb + (size_t)row * Dp + 32 + (j ^ ((row >> 2) & 1)) * 8;
      ldst[t] = KbH + 32 * (c - 4) * 16 + lane * 8;
      gstep[t] = 64 * Dp;
    } else {                // V: rows 8(c-6)..+7
      const int row = 8 * (c - 6) + (lane >> 3), j = lane & 7;
      gsrc[t] = vb + (size_t)row * Sn + (j ^ (row & 7)) * 8;
      ldst[t] = VsH + 8 * (c - 6) * 64 + lane * 8;
      gstep[t] = 64;
    }
  }

  f16v o0 = {}, o1 = {};   // O cols dh 0..31 / dh 32..63 (col 16 of o1 = lsum)

  for (int kt = 0; kt < 1024; kt += 64) {
    __syncthreads();
#pragma unroll
    for (int t = 0; t < 3; ++t) {
      gload_lds16(gsrc[t], ldst[t]);
      gsrc[t] += gstep[t];
    }
    __syncthreads();

#pragma unroll
    for (int mg = 0; mg < 2; ++mg) {        // key group: 32 keys
      const int row = 32 * mg + l31;        // key for A-frag
      const int s1 = (l31 >> 1) & 3, s2 = (l31 >> 2) & 1;
      s8v a0 = *(const s8v*)(KaH + row * 32 + ((0 | h) ^ s1) * 8);
      s8v a1 = *(const s8v*)(KaH + row * 32 + ((2 | h) ^ s1) * 8);
      s8v a2 = *(const s8v*)(KbH + row * 16 + ((h) ^ s2) * 8);
      f16v sc = {};
      sc = MFMA32(a0, qf[0], sc);
      sc = MFMA32(a1, qf[1], sc);
      sc = MFMA32(a2, qf[2], sc);           // S^T: col=q(lane&31), row=key(reg,h)
      float p[16];
#pragma unroll
      for (int r = 0; r < 16; ++r) p[r] = fexp2(sc[r]);

#pragma unroll
      for (int c2 = 0; c2 < 2; ++c2) {      // 16-key chunks of this group
        const int rb = 8 * c2;
        uint32_t w0 = packbf(p[rb + 0], p[rb + 1]);
        uint32_t w1 = packbf(p[rb + 2], p[rb + 3]);
        uint32_t w2 = packbf(p[rb + 4], p[rb + 5]);
        uint32_t w3 = packbf(p[rb + 6], p[rb + 7]);
        pl32swap(w0, w2);
        pl32swap(w1, w3);
        uint4 af = { w0, w1, w2, w3 };
        const s8v pa = __builtin_bit_cast(s8v, af);
        const int kcv = 2 * mg + c2;        // 16-key chunk index in 64-key tile
        const int vc = ((2 * kcv + h) ^ (l31 & 7)) * 8;
        const s8v v0 = *(const s8v*)(VsH + l31 * 64 + vc);
        const s8v v1 = *(const s8v*)(VsH + (32 + l31) * 64 + vc);
        o0 = MFMA32(pa, v0, o0);
        o1 = MFMA32(pa, v1, o1);
      }
    }
  }

  // ---- in-LDS combine (exact: disjoint-key partials add; v14-passing math).
  __syncthreads();
  float* scr = (float*)&smem[0][0];
  if (kg == 1) {
#pragma unroll
    for (int r = 0; r < 16; ++r) scr[r * 256 + w4 * 64 + lane] = o0[r];
  }
  __syncthreads();
  if (kg == 0) {
#pragma unroll
    for (int r = 0; r < 16; ++r) o0[r] += scr[r * 256 + w4 * 64 + lane];
  }
  __syncthreads();
  if (kg == 1) {
#pragma unroll
    for (int r = 0; r < 16; ++r) scr[r * 256 + w4 * 64 + lane] = o1[r];
  }
  __syncthreads();
  if (kg == 0) {
#pragma unroll
    for (int r = 0; r < 16; ++r) o1[r] += scr[r * 256 + w4 * 64 + lane];

    const int b = bh >> 4, hh = bh & 15;
#pragma unroll
    for (int r = 0; r < 16; ++r) {
      const int q = (r & 3) + 8 * (r >> 2) + 4 * h;
      const float lsum = __shfl(o1[r], 16 + (lane & 32), 64);  // dh48 ones row
      const float inv = 1.0f / lsum;
      const int s = q0 + w4 * 32 + q;
      const size_t base = ((size_t)(b * Sn + s)) * Dn + hh * DhN;
      og[base + l31] = f2b(o0[r] * inv);
      if (l31 < 16) og[base + 32 + l31] = f2b(o1[r] * inv);
    }
  }
}

extern "C" void kernel_launch(void* const* d_in, const int* in_sizes, int n_in,
                              void* d_out, int out_size, void* d_ws, size_t ws_size,
                              hipStream_t stream) {
  (void)in_sizes; (void)n_in; (void)out_size; (void)ws_size;
  const float* x  = (const float*)d_in[0];
  const float* Wq = (const float*)d_in[1];
  const float* bq = (const float*)d_in[2];
  const float* Wk = (const float*)d_in[3];
  const float* bk = (const float*)d_in[4];
  const float* Wv = (const float*)d_in[5];
  const float* bv = (const float*)d_in[6];
  const float* Wo = (const float*)d_in[7];
  const float* bo = (const float*)d_in[8];

  size_t off = 0;
  auto alloc = [&](size_t bytes) {
    void* p = (char*)d_ws + off;
    off += (bytes + 255) & ~(size_t)255;
    return p;
  };
  ushort* xb    = (ushort*)alloc((size_t)MS * Dn * 2);
  ushort* Wqkvb = (ushort*)alloc((size_t)3 * Dn * Dn * 2);
  ushort* Wob   = (ushort*)alloc((size_t)Dn * Dn * 2);
  ushort* qbuf  = (ushort*)alloc((size_t)Bn * Hn * Sn * Dp * 2);
  ushort* kbuf  = (ushort*)alloc((size_t)Bn * Hn * Sn * Dp * 2);
  ushort* vbuf  = (ushort*)alloc((size_t)Bn * Hn * DhN * Sn * 2);
  ushort* ao    = (ushort*)alloc((size_t)MS * Dn * 2);

  cvt_all<<<6144 + 4 * 576, 256, 0, stream>>>(x, Wq, Wk, Wv, Wo, xb, Wqkvb, Wob);

  const dim3 blk(256);
  // scale = log2(e)/sqrt(48): softmax computed in exp2 domain
  const float qscale = 0.20823510929813633f;
  gemm_qkv<<<dim3(18, MS / 128), blk, 0, stream>>>(xb, Wqkvb, bq, bk, bv,
                                                   qbuf, kbuf, vbuf, qscale);

  attn_fused<<<dim3(Sn / 128, Bn * Hn), dim3(512), 0, stream>>>(qbuf, kbuf, vbuf, ao);

  gemm_out<<<dim3(6, MS / 128), blk, 0, stream>>>(ao, Wob, bo, (float*)d_out);
}

// Round 12
// 228.476 us; speedup vs baseline: 1.1188x; 1.0205x over previous
//
#include <hip/hip_runtime.h>
#include <cstdint>
#include <cstddef>

// MultiHeadAttention: B=4, S=2048, D=768, H=16, Dh=48, fp32 I/O.
// bf16 MFMA: cvt_all -> fused QKV GEMM -> in-block split-K flash-attn -> out GEMM
// v17: (a) T5 s_setprio(1) around attn MFMA clusters ONLY (m191: +4-7% attn
// isolated; v8's regression was the bundled dbuf - this is the clean A/B).
// (b) gemm_out retiled 128x128 -> 64x128: grid 384 -> 768 blocks = exactly
// 3.0 blocks/CU, zero tail (768=3x256; was 1.5/CU -> ~25% idle). Same k0/h
// accumulation order per output element -> bit-identical numerics. Staging
// permutation reused (A: 2 slots/thread, B: 4); parity algebra carries.
// Carried: XCD swizzle all kernels, BK=64 GEMMs, in-block split-K attn
// (79.5us class), packbf, permlane32_swap, dh-pad skip, xor-swizzled frags.

typedef short s8v __attribute__((ext_vector_type(8)));    // 8 x bf16 (4 VGPRs)
typedef float f4v __attribute__((ext_vector_type(4)));    // 16x16 accumulator
typedef float f16v __attribute__((ext_vector_type(16)));  // 32x32 accumulator

static constexpr int Bn = 4, Sn = 2048, Dn = 768, Hn = 16, DhN = 48, Dp = 64;
static constexpr int MS = Bn * Sn;  // 8192 rows

#define MFMA16(a, b, c) __builtin_amdgcn_mfma_f32_16x16x32_bf16((a), (b), (c), 0, 0, 0)
#define MFMA32(a, b, c) __builtin_amdgcn_mfma_f32_32x32x16_bf16((a), (b), (c), 0, 0, 0)

__device__ __forceinline__ int swz4(int r) { return (r + (r >> 2)) & 3; }

__device__ __forceinline__ ushort f2b(float f) {
  return (ushort)((__builtin_bit_cast(uint32_t, f) + 0x8000u) >> 16);
}
// pack hi16(a+0x8000), hi16(b+0x8000) via v_perm_b32 (a -> low half)
__device__ __forceinline__ uint32_t packbf(float a, float b) {
  uint32_t ua = __builtin_bit_cast(uint32_t, a) + 0x8000u;
  uint32_t ub = __builtin_bit_cast(uint32_t, b) + 0x8000u;
  return __builtin_amdgcn_perm(ub, ua, 0x07060302u);
}
// swap upper 32 lanes of a with lower 32 lanes of b (in place, both usable)
__device__ __forceinline__ void pl32swap(uint32_t& a, uint32_t& b) {
  asm("v_permlane32_swap_b32 %0, %1" : "+v"(a), "+v"(b));
}
__device__ __forceinline__ float fexp2(float x) {
  return __builtin_amdgcn_exp2f(x);
}
__device__ __forceinline__ void gload_lds16(const ushort* g, ushort* l) {
  __builtin_amdgcn_global_load_lds(
      (const __attribute__((address_space(1))) uint32_t*)g,
      (__attribute__((address_space(3))) uint32_t*)l, 16, 0, 0);
}

// One launch converts x (6144 blocks) + 4 weights (4*576 blocks) to bf16.
__global__ void cvt_all(const float* __restrict__ x,
                        const float* __restrict__ wq, const float* __restrict__ wk,
                        const float* __restrict__ wv, const float* __restrict__ wo,
                        ushort* __restrict__ xb, ushort* __restrict__ wqkv,
                        ushort* __restrict__ wob) {
  const int bid = blockIdx.x;
  const float* src;
  ushort* dst;
  int i;
  if (bid < 6144) {
    src = x; dst = xb; i = bid * 256 + threadIdx.x;
  } else {
    const int r = (bid - 6144) / 576;
    i = ((bid - 6144) % 576) * 256 + threadIdx.x;
    src = (r == 0) ? wq : (r == 1) ? wk : (r == 2) ? wv : wo;
    dst = (r < 3) ? (wqkv + (size_t)r * Dn * Dn) : wob;
  }
  float4 f = ((const float4*)src)[i];
  ushort4 o = { f2b(f.x), f2b(f.y), f2b(f.z), f2b(f.w) };
  ((ushort4*)dst)[i] = o;
}

// ---- Fused QKV GEMM (A=W, B=x so acc regs = 4 consecutive n). Swizzled LDS.
// BK=64: 12 K-iters. XCD swizzle: nwg=1152, XCD c gets 144 consecutive cells.
__global__ __launch_bounds__(256) void gemm_qkv(
    const ushort* __restrict__ A, const ushort* __restrict__ W,
    const float* __restrict__ bq, const float* __restrict__ bk, const float* __restrict__ bv,
    ushort* __restrict__ outq, ushort* __restrict__ outk, ushort* __restrict__ outv,
    float qscale) {
  __shared__ __align__(16) ushort As[128][64];   // x rows
  __shared__ __align__(16) ushort Bs[128][64];   // W rows
  const int tid = threadIdx.x, lane = tid & 63, wave = tid >> 6;
  const int l15 = lane & 15, g = lane >> 4;
  // XCD-aware bijective relabel: hw round-robins linear id % 8 across XCDs.
  const int lin0 = blockIdx.x + blockIdx.y * 18;        // 0..1151
  const int lin = (lin0 & 7) * 144 + (lin0 >> 3);       // XCD-chunked, bijective
  const int nx = lin % 18, my = lin / 18;
  const int m0 = my * 128, n0 = nx * 128;
  const int wqm = (wave >> 1) * 64;   // weight-dim quadrant
  const int wqx = (wave & 1) * 64;    // x-dim quadrant
  f4v acc[4][4] = {};                 // [i=wtile][j=xtile]

  const ushort* agp[4];
  const ushort* bgp[4];
  ushort* lap[4];
  ushort* lbp[4];
#pragma unroll
  for (int q = 0; q < 4; ++q) {
    const int slot = q * 256 + wave * 64 + lane;   // 0..1023
    const int r = slot >> 3, sc = slot & 7;
    const int u = ((((sc & 3) ^ swz4(r & 15)) | (sc & 4)) ^ ((r & 1) << 2)) * 8;
    agp[q] = A + (size_t)(m0 + r) * Dn + u;
    bgp[q] = W + (size_t)(n0 + r) * Dn + u;
    lap[q] = &As[0][0] + slot * 8;
    lbp[q] = &Bs[0][0] + slot * 8;
  }
  const int fcol = (g ^ swz4(l15)) * 8;
  const int par = l15 & 1;

  for (int k0 = 0; k0 < Dn; k0 += 64) {
    __syncthreads();
#pragma unroll
    for (int q = 0; q < 4; ++q) {
      gload_lds16(agp[q] + k0, lap[q]);
      gload_lds16(bgp[q] + k0, lbp[q]);
    }
    __syncthreads();
#pragma unroll
    for (int h = 0; h < 2; ++h) {
      const int fc = fcol + 32 * (h ^ par);   // holds global k-substep h
      s8v wf[4], xf[4];
#pragma unroll
      for (int i = 0; i < 4; ++i) wf[i] = *(const s8v*)&Bs[wqm + i * 16 + l15][fc];
#pragma unroll
      for (int j = 0; j < 4; ++j) xf[j] = *(const s8v*)&As[wqx + j * 16 + l15][fc];
#pragma unroll
      for (int i = 0; i < 4; ++i)
#pragma unroll
        for (int j = 0; j < 4; ++j) acc[i][j] = MFMA16(wf[i], xf[j], acc[i][j]);
    }
  }

  const int region = nx / 6;                // uniform per block
  const int nbase = n0 - region * 768;
  const float* bias = (region == 0) ? bq : (region == 1) ? bk : bv;
#pragma unroll
  for (int i = 0; i < 4; ++i) {
    const int n = nbase + wqm + i * 16 + g * 4;   // 4 consecutive n, same head
    const float4 b4 = *(const float4*)&bias[n];
    const int h = n / DhN, dh = n - h * DhN;
#pragma unroll
    for (int j = 0; j < 4; ++j) {
      const int s = m0 + wqx + j * 16 + l15;
      const int b = s >> 11, srow = s & 2047;
      const int bh = b * Hn + h;
      float v0 = acc[i][j][0] + b4.x, v1 = acc[i][j][1] + b4.y;
      float v2 = acc[i][j][2] + b4.z, v3 = acc[i][j][3] + b4.w;
      if (region == 0) { v0 *= qscale; v1 *= qscale; v2 *= qscale; v3 *= qscale; }
      if (region < 2) {
        ushort4 o = { f2b(v0), f2b(v1), f2b(v2), f2b(v3) };
        ushort* dst = region ? outk : outq;
        *(ushort4*)&dst[((size_t)bh * Sn + srow) * Dp + dh] = o;
      } else {
        outv[((size_t)bh * DhN + dh + 0) * Sn + srow] = f2b(v0);
        outv[((size_t)bh * DhN + dh + 1) * Sn + srow] = f2b(v1);
        outv[((size_t)bh * DhN + dh + 2) * Sn + srow] = f2b(v2);
        outv[((size_t)bh * DhN + dh + 3) * Sn + srow] = f2b(v3);
      }
    }
  }
}

// ---- Out projection GEMM (swapped operands, float4 stores). BK=64.
// v17: 64x128 tile (M halved). Grid 128x6 = 768 blocks = exactly 3.0/CU,
// zero tail (was 384 = 1.5/CU, ~25% idle). Waves: 2x2 over (64m x 128n),
// acc[4][2]. Same k0/h accumulation order -> bit-identical numerics.
// XCD swizzle: nwg=768 (%8==0), chunk=96. LDS 24KB (As 8K + Bs 16K).
__global__ __launch_bounds__(256) void gemm_out(
    const ushort* __restrict__ A, const ushort* __restrict__ W,
    const float* __restrict__ bias, float* __restrict__ out) {
  __shared__ __align__(16) ushort As[64][64];
  __shared__ __align__(16) ushort Bs[128][64];
  const int tid = threadIdx.x, lane = tid & 63, wave = tid >> 6;
  const int l15 = lane & 15, g = lane >> 4;
  const int lin0 = blockIdx.x + blockIdx.y * 6;         // 0..767
  const int lin = (lin0 & 7) * 96 + (lin0 >> 3);        // XCD-chunked, bijective
  const int nx = lin % 6, my = lin / 6;
  const int m0 = my * 64, n0 = nx * 128;
  const int wqm = (wave >> 1) * 64;   // n-quadrant (0/64)
  const int wqx = (wave & 1) * 32;    // m-quadrant (0/32)
  f4v acc[4][2] = {};                 // [i=n-tile][j=m-tile]

  // B staging: 128 rows x 64 cols = 4 slots/thread. A: 64 rows = 2 slots.
  const ushort* agp[2];
  const ushort* bgp[4];
  ushort* lap[2];
  ushort* lbp[4];
#pragma unroll
  for (int q = 0; q < 4; ++q) {
    const int slot = q * 256 + wave * 64 + lane;   // 0..1023
    const int r = slot >> 3, sc = slot & 7;
    const int u = ((((sc & 3) ^ swz4(r & 15)) | (sc & 4)) ^ ((r & 1) << 2)) * 8;
    bgp[q] = W + (size_t)(n0 + r) * Dn + u;
    lbp[q] = &Bs[0][0] + slot * 8;
    if (q < 2) {
      agp[q] = A + (size_t)(m0 + r) * Dn + u;
      lap[q] = &As[0][0] + slot * 8;
    }
  }
  const int fcol = (g ^ swz4(l15)) * 8;
  const int par = l15 & 1;

  for (int k0 = 0; k0 < Dn; k0 += 64) {
    __syncthreads();
#pragma unroll
    for (int q = 0; q < 4; ++q) gload_lds16(bgp[q] + k0, lbp[q]);
#pragma unroll
    for (int q = 0; q < 2; ++q) gload_lds16(agp[q] + k0, lap[q]);
    __syncthreads();
#pragma unroll
    for (int h = 0; h < 2; ++h) {
      const int fc = fcol + 32 * (h ^ par);
      s8v wf[4], xf[2];
#pragma unroll
      for (int i = 0; i < 4; ++i) wf[i] = *(const s8v*)&Bs[wqm + i * 16 + l15][fc];
#pragma unroll
      for (int j = 0; j < 2; ++j) xf[j] = *(const s8v*)&As[wqx + j * 16 + l15][fc];
#pragma unroll
      for (int i = 0; i < 4; ++i)
#pragma unroll
        for (int j = 0; j < 2; ++j) acc[i][j] = MFMA16(wf[i], xf[j], acc[i][j]);
    }
  }

#pragma unroll
  for (int i = 0; i < 4; ++i) {
    const int n = n0 + wqm + i * 16 + g * 4;
    const float4 b4 = *(const float4*)&bias[n];
#pragma unroll
    for (int j = 0; j < 2; ++j) {
      const int s = m0 + wqx + j * 16 + l15;
      float4 o4 = { acc[i][j][0] + b4.x, acc[i][j][1] + b4.y,
                    acc[i][j][2] + b4.z, acc[i][j][3] + b4.w };
      *(float4*)&out[(size_t)s * Dn + n] = o4;
    }
  }
}

// ---- In-block split-K flash attention (v15 + T5 setprio). grid (16, 64),
// block 512 (8 waves = 2 key-groups x 4 q-waves of 32 q each). Group g: keys
// [1024g, 1024g+1024), 16 x 64-key tiles in its own LDS half (14KB).
// Epilogue: group 1 -> LDS scratch (transposed, conflict-free), group 0 adds
// + normalizes (lsum = dh48 ones-row col). 32 waves/CU (HW cap).
// v17: setprio(1) around QK (3 MFMA) and PV (2 MFMA) clusters - m191 recipe,
// clean A/B this time (v8 bundled it with the regressing dbuf).
__global__ __launch_bounds__(512) void attn_fused(
    const ushort* __restrict__ qg, const ushort* __restrict__ kgl,
    const ushort* __restrict__ vg, ushort* __restrict__ og) {
  __shared__ __align__(16) ushort smem[2][7168];  // per half: Ka 2048 | Kb 1024 | Vs 4096
  const int tid = threadIdx.x;
  const int lane = tid & 63;
  const int wave = tid >> 6;          // 0..7
  const int w4 = wave & 3;            // q-wave within group
  const int kg = wave >> 2;           // key-half group
  const int l31 = lane & 31;
  const int h = lane >> 5;            // 0..1
  // XCD swizzle: lin%8 = XCD c; XCD c gets heads [8c,8c+8) x all q-tiles.
  const int lin = blockIdx.x + (blockIdx.y << 4);
  const int k8 = lin >> 3;
  const int bh = (lin & 7) * 8 + (k8 >> 4);
  const int q0 = (k8 & 15) * 128;
  const ushort* qb = qg + (size_t)bh * Sn * Dp;
  const ushort* kb = kgl + (size_t)bh * Sn * Dp + (size_t)kg * 1024 * Dp;
  const ushort* vb = vg + (size_t)bh * DhN * Sn + kg * 1024;
  ushort* KaH = &smem[kg][0];         // [64][32]
  ushort* KbH = &smem[kg][2048];      // [64][16]
  ushort* VsH = &smem[kg][3072];      // [64][64]

  // static V rows 48..63 (both halves): row 48 = 1.0 (lsum), rest 0.
  ((uint32_t*)&smem[0][6144])[tid] = (tid < 32) ? 0x3F803F80u : 0u;
  ((uint32_t*)&smem[1][6144])[tid] = (tid < 32) ? 0x3F803F80u : 0u;

  // Q B-frags (n=q=lane&31, k=dh): kc 0..2 covers dh 0..47 (pad skipped)
  s8v qf[3];
#pragma unroll
  for (int kc = 0; kc < 3; ++kc)
    qf[kc] = *(const s8v*)(qb + (size_t)(q0 + w4 * 32 + l31) * Dp + kc * 16 + h * 8);

  // DMA per half: 12 x 1KB chunks, q-wave w4 takes c = w4 + 4t -> 3 each.
  const ushort* gsrc[3];
  ushort* ldst[3];
  int gstep[3];
#pragma unroll
  for (int t = 0; t < 3; ++t) {
    const int c = w4 + 4 * t;
    if (c < 4) {            // Ka: rows 16c..16c+15, dh 0..31
      const int row = 16 * c + (lane >> 2), j = lane & 3;
      gsrc[t] = kb + (size_t)row * Dp + (j ^ ((row >> 1) & 3)) * 8;
      ldst[t] = KaH + 16 * c * 32 + lane * 8;
      gstep[t] = 64 * Dp;
    } else if (c < 6) {     // Kb: rows 32(c-4)..+31, dh 32..47
      const int row = 32 * (c - 4) + (lane >> 1), j = lane & 1;
      gsrc[t] = kb + (size_t)row * Dp + 32 + (j ^ ((row >> 2) & 1)) * 8;
      ldst[t] = KbH + 32 * (c - 4) * 16 + lane * 8;
      gstep[t] = 64 * Dp;
    } else {                // V: rows 8(c-6)..+7
      const int row = 8 * (c - 6) + (lane >> 3), j = lane & 7;
      gsrc[t] = vb + (size_t)row * Sn + (j ^ (row & 7)) * 8;
      ldst[t] = VsH + 8 * (c - 6) * 64 + lane * 8;
      gstep[t] = 64;
    }
  }

  f16v o0 = {}, o1 = {};   // O cols dh 0..31 / dh 32..63 (col 16 of o1 = lsum)

  for (int kt = 0; kt < 1024; kt += 64) {
    __syncthreads();
#pragma unroll
    for (int t = 0; t < 3; ++t) {
      gload_lds16(gsrc[t], ldst[t]);
      gsrc[t] += gstep[t];
    }
    __syncthreads();

#pragma unroll
    for (int mg = 0; mg < 2; ++mg) {        // key group: 32 keys
      const int row = 32 * mg + l31;        // key for A-frag
      const int s1 = (l31 >> 1) & 3, s2 = (l31 >> 2) & 1;
      s8v a0 = *(const s8v*)(KaH + row * 32 + ((0 | h) ^ s1) * 8);
      s8v a1 = *(const s8v*)(KaH + row * 32 + ((2 | h) ^ s1) * 8);
      s8v a2 = *(const s8v*)(KbH + row * 16 + ((h) ^ s2) * 8);
      f16v sc = {};
      __builtin_amdgcn_s_setprio(1);
      sc = MFMA32(a0, qf[0], sc);
      sc = MFMA32(a1, qf[1], sc);
      sc = MFMA32(a2, qf[2], sc);           // S^T: col=q(lane&31), row=key(reg,h)
      __builtin_amdgcn_s_setprio(0);
      float p[16];
#pragma unroll
      for (int r = 0; r < 16; ++r) p[r] = fexp2(sc[r]);

#pragma unroll
      for (int c2 = 0; c2 < 2; ++c2) {      // 16-key chunks of this group
        const int rb = 8 * c2;
        uint32_t w0 = packbf(p[rb + 0], p[rb + 1]);
        uint32_t w1 = packbf(p[rb + 2], p[rb + 3]);
        uint32_t w2 = packbf(p[rb + 4], p[rb + 5]);
        uint32_t w3 = packbf(p[rb + 6], p[rb + 7]);
        pl32swap(w0, w2);
        pl32swap(w1, w3);
        uint4 af = { w0, w1, w2, w3 };
        const s8v pa = __builtin_bit_cast(s8v, af);
        const int kcv = 2 * mg + c2;        // 16-key chunk index in 64-key tile
        const int vc = ((2 * kcv + h) ^ (l31 & 7)) * 8;
        const s8v v0 = *(const s8v*)(VsH + l31 * 64 + vc);
        const s8v v1 = *(const s8v*)(VsH + (32 + l31) * 64 + vc);
        __builtin_amdgcn_s_setprio(1);
        o0 = MFMA32(pa, v0, o0);
        o1 = MFMA32(pa, v1, o1);
        __builtin_amdgcn_s_setprio(0);
      }
    }
  }

  // ---- in-LDS combine (exact: disjoint-key partials add; v14-passing math).
  __syncthreads();
  float* scr = (float*)&smem[0][0];
  if (kg == 1) {
#pragma unroll
    for (int r = 0; r < 16; ++r) scr[r * 256 + w4 * 64 + lane] = o0[r];
  }
  __syncthreads();
  if (kg == 0) {
#pragma unroll
    for (int r = 0; r < 16; ++r) o0[r] += scr[r * 256 + w4 * 64 + lane];
  }
  __syncthreads();
  if (kg == 1) {
#pragma unroll
    for (int r = 0; r < 16; ++r) scr[r * 256 + w4 * 64 + lane] = o1[r];
  }
  __syncthreads();
  if (kg == 0) {
#pragma unroll
    for (int r = 0; r < 16; ++r) o1[r] += scr[r * 256 + w4 * 64 + lane];

    const int b = bh >> 4, hh = bh & 15;
#pragma unroll
    for (int r = 0; r < 16; ++r) {
      const int q = (r & 3) + 8 * (r >> 2) + 4 * h;
      const float lsum = __shfl(o1[r], 16 + (lane & 32), 64);  // dh48 ones row
      const float inv = 1.0f / lsum;
      const int s = q0 + w4 * 32 + q;
      const size_t base = ((size_t)(b * Sn + s)) * Dn + hh * DhN;
      og[base + l31] = f2b(o0[r] * inv);
      if (l31 < 16) og[base + 32 + l31] = f2b(o1[r] * inv);
    }
  }
}

extern "C" void kernel_launch(void* const* d_in, const int* in_sizes, int n_in,
                              void* d_out, int out_size, void* d_ws, size_t ws_size,
                              hipStream_t stream) {
  (void)in_sizes; (void)n_in; (void)out_size; (void)ws_size;
  const float* x  = (const float*)d_in[0];
  const float* Wq = (const float*)d_in[1];
  const float* bq = (const float*)d_in[2];
  const float* Wk = (const float*)d_in[3];
  const float* bk = (const float*)d_in[4];
  const float* Wv = (const float*)d_in[5];
  const float* bv = (const float*)d_in[6];
  const float* Wo = (const float*)d_in[7];
  const float* bo = (const float*)d_in[8];

  size_t off = 0;
  auto alloc = [&](size_t bytes) {
    void* p = (char*)d_ws + off;
    off += (bytes + 255) & ~(size_t)255;
    return p;
  };
  ushort* xb    = (ushort*)alloc((size_t)MS * Dn * 2);
  ushort* Wqkvb = (ushort*)alloc((size_t)3 * Dn * Dn * 2);
  ushort* Wob   = (ushort*)alloc((size_t)Dn * Dn * 2);
  ushort* qbuf  = (ushort*)alloc((size_t)Bn * Hn * Sn * Dp * 2);
  ushort* kbuf  = (ushort*)alloc((size_t)Bn * Hn * Sn * Dp * 2);
  ushort* vbuf  = (ushort*)alloc((size_t)Bn * Hn * DhN * Sn * 2);
  ushort* ao    = (ushort*)alloc((size_t)MS * Dn * 2);

  cvt_all<<<6144 + 4 * 576, 256, 0, stream>>>(x, Wq, Wk, Wv, Wo, xb, Wqkvb, Wob);

  const dim3 blk(256);
  // scale = log2(e)/sqrt(48): softmax computed in exp2 domain
  const float qscale = 0.20823510929813633f;
  gemm_qkv<<<dim3(18, MS / 128), blk, 0, stream>>>(xb, Wqkvb, bq, bk, bv,
                                                   qbuf, kbuf, vbuf, qscale);

  attn_fused<<<dim3(Sn / 128, Bn * Hn), dim3(512), 0, stream>>>(qbuf, kbuf, vbuf, ao);

  gemm_out<<<dim3(6, MS / 64), blk, 0, stream>>>(ao, Wob, bo, (float*)d_out);
}